// Round 5
// baseline (377.844 us; speedup 1.0000x reference)
//
#include <hip/hip_runtime.h>
#include <math.h>

// Problem constants
#define BATCH 8
#define LTOT 4096
#define DEMB 1024
#define NH 16
#define DH 64

// ws layout (float offsets) — ~3.2 MB total
#define WS_S   0                            // S      [B][1024][16]
#define WS_SV  (WS_S + BATCH*DEMB*NH)       // sv     [B][16]
#define WS_WQ  (WS_SV + BATCH*NH)           // wq_nat [B][1024][16] (natural layout)
#define WS_C   (WS_WQ + BATCH*DEMB*NH)      // c      [B][16]
#define WS_V   (WS_C + BATCH*NH)            // V      [B][4096][16]
#define WS_KTV (WS_V + BATCH*LTOT*NH)       // ktv_g  [B][16][64]

#define FMA4(A, s, W) { (A).x += (s)*(W).x; (A).y += (s)*(W).y; (A).z += (s)*(W).z; (A).w += (s)*(W).w; }

// ---------------------------------------------------------------------------
// xw_core v5: y[l][h] = x[l][:] . W[:][h], 64 rows/block, W=[1024][16].
//   MODE 0: W=Wv, epi v=y+bv -> V[b][l][16] + sv (atomicAdd).
//   MODE 1: W=wq_nat[b], epi z=(y+c)/8 -> sigmoid -> mask -> out[b][h][l].
// 512 thr, grid B*64. W staged ONCE in 64KB LDS (permuted: logical f4
// (i=s*64+is*4+II, hq=q) at lds f4 s*256 + (II*4+q)*16 + is). Main loop has
// NO barriers (the v3 regression was the per-slice barrier's vmcnt(0) drain
// killing the prefetch); x goes global->reg with 2-slice-deep prefetch.
// Thread = (is=t&15, rg=t>>4): rows {rg, rg+32}, i's {(s*16+is)*4..+3}.
// Per wave x-load: 4 rows x 256B = 1KB coalesced, zero redundancy.
// Epilogue: shfl_xor over is (bits 0..3), 5KB LDS transpose (aliased onto W).
// LDS 64KB -> 2 blocks/CU = 16 waves; VGPR ~90 <= 128 cap (512,4).
// ---------------------------------------------------------------------------
template <int MODE>
__global__ __launch_bounds__(512, 4) void xw_core(
    const float* __restrict__ x, const float* __restrict__ Wg,
    const float* __restrict__ aux,          // MODE0: bv[16]; MODE1: cvec[B][16]
    const int* __restrict__ mask,           // MODE1 only
    float* __restrict__ outp,               // MODE0: V; MODE1: out
    float* __restrict__ sv) {               // MODE0 only
  __shared__ float lds[DEMB * NH];   // 64KB: W (compute) / ylds[64][20] (epilogue)
  __shared__ float axl[80];          // MODE1: c[16]; MODE0: sv partials [4][16]

  const int b  = blockIdx.x >> 6;
  const int l0 = (blockIdx.x & 63) * 64;
  const int t  = threadIdx.x;
  const int is = t & 15;
  const int rg = t >> 4;             // 0..31

  const float4* xg  = (const float4*)(x + ((size_t)(b * LTOT + l0)) * DEMB);
  const float4* Wf4 = (const float4*)((MODE == 0) ? Wg : (Wg + ((size_t)b << 14)));
  float4* ws4 = (float4*)lds;

  if (MODE == 1 && t < NH) axl[t] = aux[b * NH + t];

  // x prefetch: 2 slices deep, issued before W staging (deepest in queue)
  float4 xa0 = xg[rg * 256 + is];
  float4 xa1 = xg[(rg + 32) * 256 + is];
  float4 xb0 = xg[rg * 256 + 16 + is];
  float4 xb1 = xg[(rg + 32) * 256 + 16 + is];

  // stage W once: coalesced global reads, permuted LDS dst
  #pragma unroll
  for (int j = t; j < 4096; j += 512) {
    const int s = j >> 8, v = j & 255;
    ws4[s * 256 + (((v >> 2) & 3) << 6) + ((v & 3) << 4) + (v >> 4)] = Wf4[j];
  }
  __syncthreads();   // the ONLY pre-epilogue barrier

  float4 acc[2][4];  // acc[r][q].c = y[row rg+32r][h=4q+c]
  #pragma unroll
  for (int r = 0; r < 2; ++r)
    #pragma unroll
    for (int q = 0; q < 4; ++q) acc[r][q] = make_float4(0.f, 0.f, 0.f, 0.f);

  #pragma unroll 2
  for (int s = 0; s < 16; ++s) {
    float4 xc0 = make_float4(0.f, 0.f, 0.f, 0.f);
    float4 xc1 = xc0;
    if (s < 14) {
      xc0 = xg[rg * 256 + (s + 2) * 16 + is];
      xc1 = xg[(rg + 32) * 256 + (s + 2) * 16 + is];
    }
    const float4* wr = ws4 + s * 256;
    #define CSTEP(II, COMP)                                     \
    {                                                           \
      const float4 w0 = wr[((II)*4 + 0) * 16 + is];             \
      const float4 w1 = wr[((II)*4 + 1) * 16 + is];             \
      const float4 w2 = wr[((II)*4 + 2) * 16 + is];             \
      const float4 w3 = wr[((II)*4 + 3) * 16 + is];             \
      const float f0 = xa0.COMP, f1 = xa1.COMP;                 \
      FMA4(acc[0][0], f0, w0) FMA4(acc[0][1], f0, w1)           \
      FMA4(acc[0][2], f0, w2) FMA4(acc[0][3], f0, w3)           \
      FMA4(acc[1][0], f1, w0) FMA4(acc[1][1], f1, w1)           \
      FMA4(acc[1][2], f1, w2) FMA4(acc[1][3], f1, w3)           \
    }
    CSTEP(0, x) CSTEP(1, y) CSTEP(2, z) CSTEP(3, w)
    #undef CSTEP
    xa0 = xb0; xa1 = xb1; xb0 = xc0; xb1 = xc1;
  }

  // ---- reduce over the 16 is-lanes (lane bits 0..3), register-only
  #pragma unroll
  for (int m = 1; m <= 8; m <<= 1) {
    #pragma unroll
    for (int r = 0; r < 2; ++r)
      #pragma unroll
      for (int q = 0; q < 4; ++q) {
        acc[r][q].x += __shfl_xor(acc[r][q].x, m);
        acc[r][q].y += __shfl_xor(acc[r][q].y, m);
        acc[r][q].z += __shfl_xor(acc[r][q].z, m);
        acc[r][q].w += __shfl_xor(acc[r][q].w, m);
      }
  }
  __syncthreads();   // all W reads done; safe to alias ylds onto lds
  if (is == 0) {     // writers: ylds[64 rows][20 floats] (f4-stride 5)
    float4* y4 = (float4*)lds;
    #pragma unroll
    for (int q = 0; q < 4; ++q) {
      y4[rg * 5 + q] = acc[0][q];
      y4[(rg + 32) * 5 + q] = acc[1][q];
    }
  }
  __syncthreads();

  if (MODE == 0) {
    if (t < 256) {
      // thread (hq=t&3, r=t>>2): V write fully coalesced
      const int hq = t & 3, r = t >> 2;
      const float4 bv4 = ((const float4*)aux)[hq];
      float4 v = ((const float4*)lds)[r * 5 + hq];
      v.x += bv4.x; v.y += bv4.y; v.z += bv4.z; v.w += bv4.w;
      ((float4*)outp)[((size_t)(b * LTOT + l0 + r)) * 4 + hq] = v;
      // sv: reduce over r (lane bits 2..5), per-wave partial to axl
      float4 p = v;
      #pragma unroll
      for (int m = 4; m <= 32; m <<= 1) {
        p.x += __shfl_xor(p.x, m); p.y += __shfl_xor(p.y, m);
        p.z += __shfl_xor(p.z, m); p.w += __shfl_xor(p.w, m);
      }
      if ((t & 60) == 0) ((float4*)axl)[(t >> 6) * 4 + hq] = p;
    }
    __syncthreads();
    if (t < NH) {
      float s = axl[t] + axl[16 + t] + axl[32 + t] + axl[48 + t];
      atomicAdd(&sv[b * NH + t], s);
    }
  } else {
    if (t < 256) {
      // thread (h=t>>4, lq=t&15): out plane-coalesced (256B run per h)
      const int h = t >> 4, lq = t & 15;
      const float c = axl[h];
      const int4 mk = ((const int4*)(mask + (size_t)b * LTOT + l0))[lq];
      float4 p;
      const float z0 = (lds[(lq * 4 + 0) * 20 + h] + c) * 0.125f;
      const float z1 = (lds[(lq * 4 + 1) * 20 + h] + c) * 0.125f;
      const float z2 = (lds[(lq * 4 + 2) * 20 + h] + c) * 0.125f;
      const float z3 = (lds[(lq * 4 + 3) * 20 + h] + c) * 0.125f;
      p.x = 1.f / (1.f + __expf(-z0));
      p.y = 1.f / (1.f + __expf(-z1));
      p.z = 1.f / (1.f + __expf(-z2));
      p.w = 1.f / (1.f + __expf(-z3));
      if (mk.x == 0) p.x = 0.f;
      if (mk.y == 0) p.y = 0.f;
      if (mk.z == 0) p.z = 0.f;
      if (mk.w == 0) p.w = 0.f;
      ((float4*)outp)[((size_t)(b * NH + h)) * (LTOT / 4) + (l0 >> 2) + lq] = p;
    }
  }
}

// ---------------------------------------------------------------------------
// K1s v2: S[b][i][h] += sum_l x[b][l][i] * V[b][l][h].
// Block = (b, iw: 64-i window, lc: 1024-row chunk); grid 8*16*4=512, 512 thr.
// V-chunk [1024][16] staged ONCE in 64KB LDS; main loop barrier-free with
// 2-deep x prefetch. Thread (is=t&15, rg=t>>4): one i-quad x 16 heads
// (acc[4][4] f4), rows {k*32+rg}. Per wave x-load: 4 rows x 256B = 1KB.
// Per iter: 1 global + 4 broadcast LDS b128 + 16 FMA4.
// Epilogue: shfl over rg-in-wave (16,32), 8-wave LDS reduce (aliased),
// 2 atomicAdds/thread into S (4 lc-blocks contend). LDS 64KB -> 2 blocks/CU.
// ---------------------------------------------------------------------------
__global__ __launch_bounds__(512, 4) void k1s_S(
    const float* __restrict__ x, const float* __restrict__ V,
    float* __restrict__ S) {
  __shared__ float lds[DEMB * NH];   // 64KB: V-chunk (compute) / epi[8][64][16]

  const int bid = blockIdx.x;
  const int b  = bid >> 6;
  const int iw = (bid >> 2) & 15;
  const int lc = bid & 3;
  const int t  = threadIdx.x;
  const int is = t & 15;
  const int rg = t >> 4;             // 0..31

  const float4* xg = (const float4*)(x + ((size_t)(b * LTOT + lc * 1024)) * DEMB);
  const float4* vg = (const float4*)(V + ((size_t)(b * LTOT + lc * 1024)) * NH);
  float4* vl4 = (float4*)lds;
  const int xoff = iw * 16 + is;

  // x prefetch 2-deep, then stage V-chunk (coalesced), one barrier
  float4 xa = xg[(size_t)(0 * 32 + rg) * 256 + xoff];
  float4 xb = xg[(size_t)(1 * 32 + rg) * 256 + xoff];
  #pragma unroll
  for (int j = t; j < 4096; j += 512) vl4[j] = vg[j];
  __syncthreads();

  float4 acc[4][4];   // acc[c][q].hc = S[i=iw*64+is*4+c][h=4q+hc] partial
  #pragma unroll
  for (int c = 0; c < 4; ++c)
    #pragma unroll
    for (int q = 0; q < 4; ++q) acc[c][q] = make_float4(0.f, 0.f, 0.f, 0.f);

  #pragma unroll 2
  for (int k = 0; k < 32; ++k) {
    float4 xc = make_float4(0.f, 0.f, 0.f, 0.f);
    if (k < 30) xc = xg[(size_t)((k + 2) * 32 + rg) * 256 + xoff];
    const int l = k * 32 + rg;
    const float4 v0 = vl4[l * 4 + 0];
    const float4 v1 = vl4[l * 4 + 1];
    const float4 v2 = vl4[l * 4 + 2];
    const float4 v3 = vl4[l * 4 + 3];
    FMA4(acc[0][0], xa.x, v0) FMA4(acc[0][1], xa.x, v1) FMA4(acc[0][2], xa.x, v2) FMA4(acc[0][3], xa.x, v3)
    FMA4(acc[1][0], xa.y, v0) FMA4(acc[1][1], xa.y, v1) FMA4(acc[1][2], xa.y, v2) FMA4(acc[1][3], xa.y, v3)
    FMA4(acc[2][0], xa.z, v0) FMA4(acc[2][1], xa.z, v1) FMA4(acc[2][2], xa.z, v2) FMA4(acc[2][3], xa.z, v3)
    FMA4(acc[3][0], xa.w, v0) FMA4(acc[3][1], xa.w, v1) FMA4(acc[3][2], xa.w, v2) FMA4(acc[3][3], xa.w, v3)
    xa = xb; xb = xc;
  }

  // reduce over rg-within-wave (lane bits 4,5)
  #pragma unroll
  for (int m = 16; m <= 32; m <<= 1) {
    #pragma unroll
    for (int c = 0; c < 4; ++c)
      #pragma unroll
      for (int q = 0; q < 4; ++q) {
        acc[c][q].x += __shfl_xor(acc[c][q].x, m);
        acc[c][q].y += __shfl_xor(acc[c][q].y, m);
        acc[c][q].z += __shfl_xor(acc[c][q].z, m);
        acc[c][q].w += __shfl_xor(acc[c][q].w, m);
      }
  }
  __syncthreads();   // V reads done; alias epi buffer
  const int w = t >> 6;
  if ((t & 48) == 0) {   // 16 is-lanes per wave
    float* ep = lds + w * 1024 + is * 64;   // [w][i_local=is*4+c][h]
    #pragma unroll
    for (int c = 0; c < 4; ++c)
      #pragma unroll
      for (int q = 0; q < 4; ++q)
        *(float4*)&ep[c * 16 + q * 4] = acc[c][q];
  }
  __syncthreads();
  {
    const int o = t * 2;   // o < 1024: (i_local = o>>4, h = o&15), pairs
    float s0 = 0.f, s1 = 0.f;
    #pragma unroll
    for (int ww = 0; ww < 8; ++ww) {
      const float2 u = *(const float2*)&lds[ww * 1024 + o];
      s0 += u.x; s1 += u.y;
    }
    float* dst = &S[((size_t)b << 14) + (size_t)(iw * 64 + (o >> 4)) * NH + (o & 15)];
    atomicAdd(dst, s0);
    atomicAdd(dst + 1, s1);
  }
}

// ---------------------------------------------------------------------------
// K2a: ktv[b][h][d] = sum_i Wk[i][h*64+d]*S[b][i][h] + bk[h*64+d]*sv[b][h];
//      cvec[b][h] = sum_d bq[h*64+d]*ktv[d].  grid B*16, 256 thr.
// ---------------------------------------------------------------------------
__global__ __launch_bounds__(256) void k2a_ktv(
    const float* __restrict__ Wk, const float* __restrict__ bk,
    const float* __restrict__ bq,
    const float* __restrict__ S, const float* __restrict__ sv,
    float* __restrict__ ktv_g, float* __restrict__ cvec) {
  __shared__ float part[16][64];
  __shared__ float ktv[DH];
  const int b = blockIdx.x >> 4;
  const int h = blockIdx.x & 15;
  const int t = threadIdx.x;
  const float* Sb = S + ((size_t)b << 14);
  const int d4 = t & 15, iseg = t >> 4;
  const float* wkb = Wk + h * DH + d4 * 4;
  float4 kp = {0.f, 0.f, 0.f, 0.f};
  #pragma unroll 4
  for (int i = iseg * 64; i < iseg * 64 + 64; ++i) {
    const float4 w4 = *(const float4*)&wkb[(size_t)i * DEMB];
    const float sS = Sb[i * NH + h];
    FMA4(kp, sS, w4)
  }
  *(float4*)&part[iseg][d4 * 4] = kp;
  __syncthreads();
  if (t < 64) {
    float s2 = 0.f;
    #pragma unroll
    for (int g = 0; g < 16; ++g) s2 += part[g][t];
    s2 += bk[h * DH + t] * sv[b * NH + h];
    ktv[t] = s2;
    ktv_g[(b * NH + h) * DH + t] = s2;
  }
  __syncthreads();
  if (t < 64) {
    float p = bq[h * DH + t] * ktv[t];
    p += __shfl_xor(p, 1);  p += __shfl_xor(p, 2);  p += __shfl_xor(p, 4);
    p += __shfl_xor(p, 8);  p += __shfl_xor(p, 16); p += __shfl_xor(p, 32);
    if (t == 0) cvec[b * NH + h] = p;
  }
}

// ---------------------------------------------------------------------------
// K2b: wq_nat[b][i][h] = sum_d Wq[i][h*64+d]*ktv[b][h][d].  grid B*16, 256 thr.
// ---------------------------------------------------------------------------
__global__ __launch_bounds__(256) void k2b_wq(
    const float* __restrict__ Wq, const float* __restrict__ ktv_g,
    float* __restrict__ wq_nat) {
  __shared__ float kq[DEMB];
  __shared__ float ylds[64 * 20];
  const int b = blockIdx.x >> 4;
  const int i0 = (blockIdx.x & 15) * 64;
  const int t = threadIdx.x;
  ((float4*)kq)[t] = ((const float4*)(ktv_g + (size_t)b * DEMB))[t];
  __syncthreads();

  const int jq = t & 15, rq = t >> 4;
  const float4* wq4 = (const float4*)(Wq + (size_t)i0 * DEMB);
  float a[4][16];
  #pragma unroll
  for (int k = 0; k < 4; ++k)
    #pragma unroll
    for (int s = 0; s < 16; ++s) a[k][s] = 0.f;

  #pragma unroll 4
  for (int s = 0; s < 16; ++s) {
    const float4 kv = ((const float4*)kq)[s * 16 + jq];
    #pragma unroll
    for (int k = 0; k < 4; ++k) {
      const float4 w = wq4[(size_t)(rq + 16 * k) * 256 + s * 16 + jq];
      a[k][s] += w.x * kv.x + w.y * kv.y + w.z * kv.z + w.w * kv.w;
    }
  }
  #pragma unroll
  for (int m = 1; m <= 8; m <<= 1)
    #pragma unroll
    for (int k = 0; k < 4; ++k)
      #pragma unroll
      for (int s = 0; s < 16; ++s) a[k][s] += __shfl_xor(a[k][s], m);

  if (jq == 0) {
    #pragma unroll
    for (int k = 0; k < 4; ++k)
      #pragma unroll
      for (int sq = 0; sq < 4; ++sq)
        ((float4*)ylds)[(rq + 16 * k) * 5 + sq] =
            make_float4(a[k][sq * 4], a[k][sq * 4 + 1], a[k][sq * 4 + 2], a[k][sq * 4 + 3]);
  }
  __syncthreads();
  const int hq = t & 3, r = t >> 2;
  ((float4*)wq_nat)[((size_t)b << 12) + (size_t)(i0 + r) * 4 + hq] =
      ((const float4*)ylds)[r * 5 + hq];
}

extern "C" void kernel_launch(void* const* d_in, const int* in_sizes, int n_in,
                              void* d_out, int out_size, void* d_ws, size_t ws_size,
                              hipStream_t stream) {
  const float* x  = (const float*)d_in[0];
  const int* mask = (const int*)d_in[1];
  const float* Wq = (const float*)d_in[2];
  const float* bq = (const float*)d_in[3];
  const float* Wk = (const float*)d_in[4];
  const float* bk = (const float*)d_in[5];
  const float* Wv = (const float*)d_in[6];
  const float* bv = (const float*)d_in[7];
  float* out = (float*)d_out;
  float* ws = (float*)d_ws;

  float* S      = ws + WS_S;
  float* sv     = ws + WS_SV;
  float* wq_nat = ws + WS_WQ;
  float* cvec   = ws + WS_C;
  float* V      = ws + WS_V;
  float* ktv_g  = ws + WS_KTV;

  hipMemsetAsync(sv, 0, BATCH * NH * sizeof(float), stream);
  hipMemsetAsync(S, 0, (size_t)BATCH * DEMB * NH * sizeof(float), stream);

  xw_core<0><<<dim3(BATCH * 64), dim3(512), 0, stream>>>(x, Wv, bv, nullptr, V, sv);
  k1s_S<<<dim3(BATCH * 64), dim3(512), 0, stream>>>(x, V, S);
  k2a_ktv<<<dim3(BATCH * NH), dim3(256), 0, stream>>>(Wk, bk, bq, S, sv, ktv_g, cvec);
  k2b_wq<<<dim3(BATCH * NH), dim3(256), 0, stream>>>(Wq, ktv_g, wq_nat);
  xw_core<1><<<dim3(BATCH * 64), dim3(512), 0, stream>>>(x, wq_nat, cvec, mask, out, nullptr);
}

// Round 6
// 320.427 us; speedup vs baseline: 1.1792x; 1.1792x over previous
//
#include <hip/hip_runtime.h>
#include <math.h>

// Problem constants
#define BATCH 8
#define LTOT 4096
#define DEMB 1024
#define NH 16
#define DH 64

// ws layout (float offsets) — ~3.2 MB total
#define WS_S   0                            // S      [B][1024][16]
#define WS_SV  (WS_S + BATCH*DEMB*NH)       // sv     [B][16]
#define WS_WQ  (WS_SV + BATCH*NH)           // wq_nat [B][1024][16] (natural layout)
#define WS_C   (WS_WQ + BATCH*DEMB*NH)      // c      [B][16]
#define WS_V   (WS_C + BATCH*NH)            // V      [B][4096][16]
#define WS_KTV (WS_V + BATCH*LTOT*NH)       // ktv_g  [B][16][64]

#define FMA4(A, s, W) { (A).x += (s)*(W).x; (A).y += (s)*(W).y; (A).z += (s)*(W).z; (A).w += (s)*(W).w; }

// ---------------------------------------------------------------------------
// xw_core v6: y[l][h] = x[l][:] . W[:][h], 64 rows/block, W=[1024][16].
// Identical to v5 except __launch_bounds__(512,2): v5's (512,4) produced a
// 64-VGPR cap (rocprof VGPR_Count=64) and the ~100-VGPR working set spilled
// to scratch — 120 MB/dispatch of scratch writes (WRITE_SIZE 122MB vs 2MB
// legitimate), VALUBusy 8.7%, 98us. (512,2) caps at >=128 VGPR: no spill.
// Occupancy is LDS-bound anyway (64KB -> 2 blocks/CU = 16 waves).
// ---------------------------------------------------------------------------
template <int MODE>
__global__ __launch_bounds__(512, 2) void xw_core(
    const float* __restrict__ x, const float* __restrict__ Wg,
    const float* __restrict__ aux,          // MODE0: bv[16]; MODE1: cvec[B][16]
    const int* __restrict__ mask,           // MODE1 only
    float* __restrict__ outp,               // MODE0: V; MODE1: out
    float* __restrict__ sv) {               // MODE0 only
  __shared__ float lds[DEMB * NH];   // 64KB: W (compute) / ylds[64][20] (epilogue)
  __shared__ float axl[80];          // MODE1: c[16]; MODE0: sv partials [4][16]

  const int b  = blockIdx.x >> 6;
  const int l0 = (blockIdx.x & 63) * 64;
  const int t  = threadIdx.x;
  const int is = t & 15;
  const int rg = t >> 4;             // 0..31

  const float4* xg  = (const float4*)(x + ((size_t)(b * LTOT + l0)) * DEMB);
  const float4* Wf4 = (const float4*)((MODE == 0) ? Wg : (Wg + ((size_t)b << 14)));
  float4* ws4 = (float4*)lds;

  if (MODE == 1 && t < NH) axl[t] = aux[b * NH + t];

  // x prefetch: 2 slices deep, issued before W staging (deepest in queue)
  float4 xa0 = xg[rg * 256 + is];
  float4 xa1 = xg[(rg + 32) * 256 + is];
  float4 xb0 = xg[rg * 256 + 16 + is];
  float4 xb1 = xg[(rg + 32) * 256 + 16 + is];

  // stage W once: coalesced global reads, permuted LDS dst
  #pragma unroll
  for (int j = t; j < 4096; j += 512) {
    const int s = j >> 8, v = j & 255;
    ws4[s * 256 + (((v >> 2) & 3) << 6) + ((v & 3) << 4) + (v >> 4)] = Wf4[j];
  }
  __syncthreads();   // the ONLY pre-epilogue barrier

  float4 acc[2][4];  // acc[r][q].c = y[row rg+32r][h=4q+c]
  #pragma unroll
  for (int r = 0; r < 2; ++r)
    #pragma unroll
    for (int q = 0; q < 4; ++q) acc[r][q] = make_float4(0.f, 0.f, 0.f, 0.f);

  #pragma unroll 2
  for (int s = 0; s < 16; ++s) {
    float4 xc0 = make_float4(0.f, 0.f, 0.f, 0.f);
    float4 xc1 = xc0;
    if (s < 14) {
      xc0 = xg[rg * 256 + (s + 2) * 16 + is];
      xc1 = xg[(rg + 32) * 256 + (s + 2) * 16 + is];
    }
    const float4* wr = ws4 + s * 256;
    #define CSTEP(II, COMP)                                     \
    {                                                           \
      const float4 w0 = wr[((II)*4 + 0) * 16 + is];             \
      const float4 w1 = wr[((II)*4 + 1) * 16 + is];             \
      const float4 w2 = wr[((II)*4 + 2) * 16 + is];             \
      const float4 w3 = wr[((II)*4 + 3) * 16 + is];             \
      const float f0 = xa0.COMP, f1 = xa1.COMP;                 \
      FMA4(acc[0][0], f0, w0) FMA4(acc[0][1], f0, w1)           \
      FMA4(acc[0][2], f0, w2) FMA4(acc[0][3], f0, w3)           \
      FMA4(acc[1][0], f1, w0) FMA4(acc[1][1], f1, w1)           \
      FMA4(acc[1][2], f1, w2) FMA4(acc[1][3], f1, w3)           \
    }
    CSTEP(0, x) CSTEP(1, y) CSTEP(2, z) CSTEP(3, w)
    #undef CSTEP
    xa0 = xb0; xa1 = xb1; xb0 = xc0; xb1 = xc1;
  }

  // ---- reduce over the 16 is-lanes (lane bits 0..3), register-only
  #pragma unroll
  for (int m = 1; m <= 8; m <<= 1) {
    #pragma unroll
    for (int r = 0; r < 2; ++r)
      #pragma unroll
      for (int q = 0; q < 4; ++q) {
        acc[r][q].x += __shfl_xor(acc[r][q].x, m);
        acc[r][q].y += __shfl_xor(acc[r][q].y, m);
        acc[r][q].z += __shfl_xor(acc[r][q].z, m);
        acc[r][q].w += __shfl_xor(acc[r][q].w, m);
      }
  }
  __syncthreads();   // all W reads done; safe to alias ylds onto lds
  if (is == 0) {     // writers: ylds[64 rows][20 floats] (f4-stride 5)
    float4* y4 = (float4*)lds;
    #pragma unroll
    for (int q = 0; q < 4; ++q) {
      y4[rg * 5 + q] = acc[0][q];
      y4[(rg + 32) * 5 + q] = acc[1][q];
    }
  }
  __syncthreads();

  if (MODE == 0) {
    if (t < 256) {
      // thread (hq=t&3, r=t>>2): V write fully coalesced
      const int hq = t & 3, r = t >> 2;
      const float4 bv4 = ((const float4*)aux)[hq];
      float4 v = ((const float4*)lds)[r * 5 + hq];
      v.x += bv4.x; v.y += bv4.y; v.z += bv4.z; v.w += bv4.w;
      ((float4*)outp)[((size_t)(b * LTOT + l0 + r)) * 4 + hq] = v;
      // sv: reduce over r (lane bits 2..5), per-wave partial to axl
      float4 p = v;
      #pragma unroll
      for (int m = 4; m <= 32; m <<= 1) {
        p.x += __shfl_xor(p.x, m); p.y += __shfl_xor(p.y, m);
        p.z += __shfl_xor(p.z, m); p.w += __shfl_xor(p.w, m);
      }
      if ((t & 60) == 0) ((float4*)axl)[(t >> 6) * 4 + hq] = p;
    }
    __syncthreads();
    if (t < NH) {
      float s = axl[t] + axl[16 + t] + axl[32 + t] + axl[48 + t];
      atomicAdd(&sv[b * NH + t], s);
    }
  } else {
    if (t < 256) {
      // thread (h=t>>4, lq=t&15): out plane-coalesced (256B run per h)
      const int h = t >> 4, lq = t & 15;
      const float c = axl[h];
      const int4 mk = ((const int4*)(mask + (size_t)b * LTOT + l0))[lq];
      float4 p;
      const float z0 = (lds[(lq * 4 + 0) * 20 + h] + c) * 0.125f;
      const float z1 = (lds[(lq * 4 + 1) * 20 + h] + c) * 0.125f;
      const float z2 = (lds[(lq * 4 + 2) * 20 + h] + c) * 0.125f;
      const float z3 = (lds[(lq * 4 + 3) * 20 + h] + c) * 0.125f;
      p.x = 1.f / (1.f + __expf(-z0));
      p.y = 1.f / (1.f + __expf(-z1));
      p.z = 1.f / (1.f + __expf(-z2));
      p.w = 1.f / (1.f + __expf(-z3));
      if (mk.x == 0) p.x = 0.f;
      if (mk.y == 0) p.y = 0.f;
      if (mk.z == 0) p.z = 0.f;
      if (mk.w == 0) p.w = 0.f;
      ((float4*)outp)[((size_t)(b * NH + h)) * (LTOT / 4) + (l0 >> 2) + lq] = p;
    }
  }
}

// ---------------------------------------------------------------------------
// K1s v3: S[b][i][h] += sum_l x[b][l][i] * V[b][l][h].
// Identical to v2 except __launch_bounds__(512,2): acc[4][4] alone is 64
// VGPRs — under v2's 64-VGPR cap this spilled every accumulator to scratch.
// ---------------------------------------------------------------------------
__global__ __launch_bounds__(512, 2) void k1s_S(
    const float* __restrict__ x, const float* __restrict__ V,
    float* __restrict__ S) {
  __shared__ float lds[DEMB * NH];   // 64KB: V-chunk (compute) / epi[8][64][16]

  const int bid = blockIdx.x;
  const int b  = bid >> 6;
  const int iw = (bid >> 2) & 15;
  const int lc = bid & 3;
  const int t  = threadIdx.x;
  const int is = t & 15;
  const int rg = t >> 4;             // 0..31

  const float4* xg = (const float4*)(x + ((size_t)(b * LTOT + lc * 1024)) * DEMB);
  const float4* vg = (const float4*)(V + ((size_t)(b * LTOT + lc * 1024)) * NH);
  float4* vl4 = (float4*)lds;
  const int xoff = iw * 16 + is;

  // x prefetch 2-deep, then stage V-chunk (coalesced), one barrier
  float4 xa = xg[(size_t)(0 * 32 + rg) * 256 + xoff];
  float4 xb = xg[(size_t)(1 * 32 + rg) * 256 + xoff];
  #pragma unroll
  for (int j = t; j < 4096; j += 512) vl4[j] = vg[j];
  __syncthreads();

  float4 acc[4][4];   // acc[c][q].hc = S[i=iw*64+is*4+c][h=4q+hc] partial
  #pragma unroll
  for (int c = 0; c < 4; ++c)
    #pragma unroll
    for (int q = 0; q < 4; ++q) acc[c][q] = make_float4(0.f, 0.f, 0.f, 0.f);

  #pragma unroll 2
  for (int k = 0; k < 32; ++k) {
    float4 xc = make_float4(0.f, 0.f, 0.f, 0.f);
    if (k < 30) xc = xg[(size_t)((k + 2) * 32 + rg) * 256 + xoff];
    const int l = k * 32 + rg;
    const float4 v0 = vl4[l * 4 + 0];
    const float4 v1 = vl4[l * 4 + 1];
    const float4 v2 = vl4[l * 4 + 2];
    const float4 v3 = vl4[l * 4 + 3];
    FMA4(acc[0][0], xa.x, v0) FMA4(acc[0][1], xa.x, v1) FMA4(acc[0][2], xa.x, v2) FMA4(acc[0][3], xa.x, v3)
    FMA4(acc[1][0], xa.y, v0) FMA4(acc[1][1], xa.y, v1) FMA4(acc[1][2], xa.y, v2) FMA4(acc[1][3], xa.y, v3)
    FMA4(acc[2][0], xa.z, v0) FMA4(acc[2][1], xa.z, v1) FMA4(acc[2][2], xa.z, v2) FMA4(acc[2][3], xa.z, v3)
    FMA4(acc[3][0], xa.w, v0) FMA4(acc[3][1], xa.w, v1) FMA4(acc[3][2], xa.w, v2) FMA4(acc[3][3], xa.w, v3)
    xa = xb; xb = xc;
  }

  // reduce over rg-within-wave (lane bits 4,5)
  #pragma unroll
  for (int m = 16; m <= 32; m <<= 1) {
    #pragma unroll
    for (int c = 0; c < 4; ++c)
      #pragma unroll
      for (int q = 0; q < 4; ++q) {
        acc[c][q].x += __shfl_xor(acc[c][q].x, m);
        acc[c][q].y += __shfl_xor(acc[c][q].y, m);
        acc[c][q].z += __shfl_xor(acc[c][q].z, m);
        acc[c][q].w += __shfl_xor(acc[c][q].w, m);
      }
  }
  __syncthreads();   // V reads done; alias epi buffer
  const int w = t >> 6;
  if ((t & 48) == 0) {   // 16 is-lanes per wave
    float* ep = lds + w * 1024 + is * 64;   // [w][i_local=is*4+c][h]
    #pragma unroll
    for (int c = 0; c < 4; ++c)
      #pragma unroll
      for (int q = 0; q < 4; ++q)
        *(float4*)&ep[c * 16 + q * 4] = acc[c][q];
  }
  __syncthreads();
  {
    const int o = t * 2;   // o < 1024: (i_local = o>>4, h = o&15), pairs
    float s0 = 0.f, s1 = 0.f;
    #pragma unroll
    for (int ww = 0; ww < 8; ++ww) {
      const float2 u = *(const float2*)&lds[ww * 1024 + o];
      s0 += u.x; s1 += u.y;
    }
    float* dst = &S[((size_t)b << 14) + (size_t)(iw * 64 + (o >> 4)) * NH + (o & 15)];
    atomicAdd(dst, s0);
    atomicAdd(dst + 1, s1);
  }
}

// ---------------------------------------------------------------------------
// K2a: ktv[b][h][d] = sum_i Wk[i][h*64+d]*S[b][i][h] + bk[h*64+d]*sv[b][h];
//      cvec[b][h] = sum_d bq[h*64+d]*ktv[d].  grid B*16, 256 thr.
// ---------------------------------------------------------------------------
__global__ __launch_bounds__(256) void k2a_ktv(
    const float* __restrict__ Wk, const float* __restrict__ bk,
    const float* __restrict__ bq,
    const float* __restrict__ S, const float* __restrict__ sv,
    float* __restrict__ ktv_g, float* __restrict__ cvec) {
  __shared__ float part[16][64];
  __shared__ float ktv[DH];
  const int b = blockIdx.x >> 4;
  const int h = blockIdx.x & 15;
  const int t = threadIdx.x;
  const float* Sb = S + ((size_t)b << 14);
  const int d4 = t & 15, iseg = t >> 4;
  const float* wkb = Wk + h * DH + d4 * 4;
  float4 kp = {0.f, 0.f, 0.f, 0.f};
  #pragma unroll 4
  for (int i = iseg * 64; i < iseg * 64 + 64; ++i) {
    const float4 w4 = *(const float4*)&wkb[(size_t)i * DEMB];
    const float sS = Sb[i * NH + h];
    FMA4(kp, sS, w4)
  }
  *(float4*)&part[iseg][d4 * 4] = kp;
  __syncthreads();
  if (t < 64) {
    float s2 = 0.f;
    #pragma unroll
    for (int g = 0; g < 16; ++g) s2 += part[g][t];
    s2 += bk[h * DH + t] * sv[b * NH + h];
    ktv[t] = s2;
    ktv_g[(b * NH + h) * DH + t] = s2;
  }
  __syncthreads();
  if (t < 64) {
    float p = bq[h * DH + t] * ktv[t];
    p += __shfl_xor(p, 1);  p += __shfl_xor(p, 2);  p += __shfl_xor(p, 4);
    p += __shfl_xor(p, 8);  p += __shfl_xor(p, 16); p += __shfl_xor(p, 32);
    if (t == 0) cvec[b * NH + h] = p;
  }
}

// ---------------------------------------------------------------------------
// K2b: wq_nat[b][i][h] = sum_d Wq[i][h*64+d]*ktv[b][h][d].  grid B*16, 256 thr.
// ---------------------------------------------------------------------------
__global__ __launch_bounds__(256) void k2b_wq(
    const float* __restrict__ Wq, const float* __restrict__ ktv_g,
    float* __restrict__ wq_nat) {
  __shared__ float kq[DEMB];
  __shared__ float ylds[64 * 20];
  const int b = blockIdx.x >> 4;
  const int i0 = (blockIdx.x & 15) * 64;
  const int t = threadIdx.x;
  ((float4*)kq)[t] = ((const float4*)(ktv_g + (size_t)b * DEMB))[t];
  __syncthreads();

  const int jq = t & 15, rq = t >> 4;
  const float4* wq4 = (const float4*)(Wq + (size_t)i0 * DEMB);
  float a[4][16];
  #pragma unroll
  for (int k = 0; k < 4; ++k)
    #pragma unroll
    for (int s = 0; s < 16; ++s) a[k][s] = 0.f;

  #pragma unroll 4
  for (int s = 0; s < 16; ++s) {
    const float4 kv = ((const float4*)kq)[s * 16 + jq];
    #pragma unroll
    for (int k = 0; k < 4; ++k) {
      const float4 w = wq4[(size_t)(rq + 16 * k) * 256 + s * 16 + jq];
      a[k][s] += w.x * kv.x + w.y * kv.y + w.z * kv.z + w.w * kv.w;
    }
  }
  #pragma unroll
  for (int m = 1; m <= 8; m <<= 1)
    #pragma unroll
    for (int k = 0; k < 4; ++k)
      #pragma unroll
      for (int s = 0; s < 16; ++s) a[k][s] += __shfl_xor(a[k][s], m);

  if (jq == 0) {
    #pragma unroll
    for (int k = 0; k < 4; ++k)
      #pragma unroll
      for (int sq = 0; sq < 4; ++sq)
        ((float4*)ylds)[(rq + 16 * k) * 5 + sq] =
            make_float4(a[k][sq * 4], a[k][sq * 4 + 1], a[k][sq * 4 + 2], a[k][sq * 4 + 3]);
  }
  __syncthreads();
  const int hq = t & 3, r = t >> 2;
  ((float4*)wq_nat)[((size_t)b << 12) + (size_t)(i0 + r) * 4 + hq] =
      ((const float4*)ylds)[r * 5 + hq];
}

extern "C" void kernel_launch(void* const* d_in, const int* in_sizes, int n_in,
                              void* d_out, int out_size, void* d_ws, size_t ws_size,
                              hipStream_t stream) {
  const float* x  = (const float*)d_in[0];
  const int* mask = (const int*)d_in[1];
  const float* Wq = (const float*)d_in[2];
  const float* bq = (const float*)d_in[3];
  const float* Wk = (const float*)d_in[4];
  const float* bk = (const float*)d_in[5];
  const float* Wv = (const float*)d_in[6];
  const float* bv = (const float*)d_in[7];
  float* out = (float*)d_out;
  float* ws = (float*)d_ws;

  float* S      = ws + WS_S;
  float* sv     = ws + WS_SV;
  float* wq_nat = ws + WS_WQ;
  float* cvec   = ws + WS_C;
  float* V      = ws + WS_V;
  float* ktv_g  = ws + WS_KTV;

  hipMemsetAsync(sv, 0, BATCH * NH * sizeof(float), stream);
  hipMemsetAsync(S, 0, (size_t)BATCH * DEMB * NH * sizeof(float), stream);

  xw_core<0><<<dim3(BATCH * 64), dim3(512), 0, stream>>>(x, Wv, bv, nullptr, V, sv);
  k1s_S<<<dim3(BATCH * 64), dim3(512), 0, stream>>>(x, V, S);
  k2a_ktv<<<dim3(BATCH * NH), dim3(256), 0, stream>>>(Wk, bk, bq, S, sv, ktv_g, cvec);
  k2b_wq<<<dim3(BATCH * NH), dim3(256), 0, stream>>>(Wq, ktv_g, wq_nat);
  xw_core<1><<<dim3(BATCH * 64), dim3(512), 0, stream>>>(x, wq_nat, cvec, mask, out, nullptr);
}